// Round 5
// baseline (224.603 us; speedup 1.0000x reference)
//
#include <hip/hip_runtime.h>
#include <math.h>

#define B_ 4
#define S_ 2048
#define H_ 16
#define D_ 64
#define C_ 128
#define NC_ (S_ / C_)   // 16 chunks per sequence
#define BH_ (B_ * H_)   // 64 sequences
#define SPLIT_ 4

// ---------------------------------------------------------------------------
// Kernel 1: per-chunk KV outer-product sums.  KV[bh,c][dk][dv] = sum_s k*v
// grid = BH_*NC_ blocks of 256 threads.  LDS 64 KB -> 2 blocks/CU.
// ---------------------------------------------------------------------------
__global__ __launch_bounds__(256) void kv_chunk_kernel(
    const float* __restrict__ qk, const float* __restrict__ v,
    float* __restrict__ kvbuf)
{
  __shared__ float Kl[C_][D_];   // 32 KB
  __shared__ float Vl[C_][D_];   // 32 KB
  const int bid = blockIdx.x;
  const int bh = bid / NC_, c = bid % NC_;
  const int b = bh / H_, h = bh % H_;
  const int t0 = c * C_;
  const int tid = threadIdx.x;

  // k[b,t,h,:] = qk[(((b*S+t)*2+1)*H + h)*D + :]
  const size_t kbase = (((size_t)b * S_ * 2 + 1) * H_ + h) * D_;
  const size_t vbase = (((size_t)b * S_) * H_ + h) * D_;

  #pragma unroll
  for (int i = 0; i < 8; ++i) {
    int f = tid + i * 256;            // float4 index 0..2047
    int row = f >> 4, c4 = (f & 15) << 2;
    size_t t = (size_t)t0 + row;
    *reinterpret_cast<float4*>(&Kl[row][c4]) =
        *reinterpret_cast<const float4*>(qk + kbase + t * (2 * H_ * D_) + c4);
    *reinterpret_cast<float4*>(&Vl[row][c4]) =
        *reinterpret_cast<const float4*>(v + vbase + t * (H_ * D_) + c4);
  }
  __syncthreads();

  const int dkt = tid >> 4;   // 0..15 -> dk tile of 4
  const int dvt = tid & 15;   // 0..15 -> dv tile of 4
  float acc[4][4] = {};
  #pragma unroll 4
  for (int s = 0; s < C_; ++s) {
    float4 k4 = *reinterpret_cast<const float4*>(&Kl[s][dkt * 4]);
    float4 v4 = *reinterpret_cast<const float4*>(&Vl[s][dvt * 4]);
    float kk[4] = {k4.x, k4.y, k4.z, k4.w};
    float vv[4] = {v4.x, v4.y, v4.z, v4.w};
    #pragma unroll
    for (int a = 0; a < 4; ++a)
      #pragma unroll
      for (int e = 0; e < 4; ++e)
        acc[a][e] += kk[a] * vv[e];
  }
  float* outp = kvbuf + (size_t)bid * (D_ * D_);
  #pragma unroll
  for (int a = 0; a < 4; ++a) {
    float4 o = make_float4(acc[a][0], acc[a][1], acc[a][2], acc[a][3]);
    *reinterpret_cast<float4*>(outp + (dkt * 4 + a) * D_ + dvt * 4) = o;
  }
}

// ---------------------------------------------------------------------------
// Kernel 2: in-place EXCLUSIVE prefix sum of the D*D states over chunks.
// grid = BH_*SPLIT_ blocks; each block owns 1024 floats of the 4096.
// ---------------------------------------------------------------------------
__global__ __launch_bounds__(256) void prefix_kernel(float* __restrict__ kvbuf)
{
  const int bid = blockIdx.x;
  const int bh = bid / SPLIT_, part = bid % SPLIT_;
  const size_t off = (size_t)part * 1024 + (size_t)threadIdx.x * 4;
  float4 run = make_float4(0.f, 0.f, 0.f, 0.f);
  for (int c = 0; c < NC_; ++c) {
    float* p = kvbuf + ((size_t)bh * NC_ + c) * (D_ * D_) + off;
    float4 t = *reinterpret_cast<float4*>(p);
    *reinterpret_cast<float4*>(p) = run;               // exclusive prefix
    run.x += t.x; run.y += t.y; run.z += t.z; run.w += t.w;
  }
}

// ---------------------------------------------------------------------------
// Kernel 3: out[t] = ( Q[t]·M_prefix + sum_{s<=t in chunk} (q·k_s) v_s ) * exp(-n)
// grid = BH_*NC_ blocks of 256 threads.  Thread owns 8 t-rows x 4 dv cols.
// LDS exactly 80 KB -> 2 blocks/CU.
// ---------------------------------------------------------------------------
__global__ __launch_bounds__(256) void out_kernel(
    const float* __restrict__ qk, const float* __restrict__ v,
    const float* __restrict__ nrm, const float* __restrict__ kvbuf,
    float* __restrict__ outp)
{
  __shared__ float Qt[D_][C_];    // 32 KB  Qt[d][t]  (transposed -> conflict-free)
  __shared__ float Ml[D_][D_];    // 16 KB  prefix state
  __shared__ float Kt[D_][32];    // 8 KB   Kt[d][s]  (transposed, per s-tile)
  __shared__ float Vl[32][D_];    // 8 KB   per s-tile
  __shared__ float Sc[C_][32];    // 16 KB  score redistribution buffer

  const int bid = blockIdx.x;
  const int bh = bid / NC_, c = bid % NC_;
  const int b = bh / H_, h = bh % H_;
  const int t0 = c * C_;
  const int tid = threadIdx.x;

  // ---- stage Q transposed ----
  {
    const int t = tid >> 1;
    const int d0 = (tid & 1) * 32;
    const float* qrow =
        qk + ((((size_t)b * S_ + t0 + t) * 2 + 0) * H_ + h) * D_ + d0;
    float tmp[32];
    #pragma unroll
    for (int i = 0; i < 8; ++i) {
      float4 x = *reinterpret_cast<const float4*>(qrow + i * 4);
      tmp[i*4+0] = x.x; tmp[i*4+1] = x.y; tmp[i*4+2] = x.z; tmp[i*4+3] = x.w;
    }
    #pragma unroll
    for (int i = 0; i < 32; ++i) Qt[d0 + i][t] = tmp[i];
  }
  // ---- stage M ----
  {
    const float* msrc = kvbuf + (size_t)bid * (D_ * D_);
    float* mdst = &Ml[0][0];
    #pragma unroll
    for (int i = 0; i < 4; ++i) {
      int f = (tid + i * 256) * 4;
      *reinterpret_cast<float4*>(mdst + f) =
          *reinterpret_cast<const float4*>(msrc + f);
    }
  }
  __syncthreads();

  const int tg = tid >> 4;        // 0..15  -> t rows tb..tb+7
  const int dvg = tid & 15;       // 0..15  -> dv cols dvg*4..+3
  const int tb = tg * 8;
  float acc[8][4] = {};

  // ---- phase A: cross-chunk  acc += Q[t][dk] * M[dk][dv] ----
  if (c > 0) {
    #pragma unroll 4
    for (int dk = 0; dk < D_; ++dk) {
      float4 m4 = *reinterpret_cast<const float4*>(&Ml[dk][dvg * 4]);
      float4 qa = *reinterpret_cast<const float4*>(&Qt[dk][tb]);
      float4 qb = *reinterpret_cast<const float4*>(&Qt[dk][tb + 4]);
      float qv[8] = {qa.x, qa.y, qa.z, qa.w, qb.x, qb.y, qb.z, qb.w};
      float mv[4] = {m4.x, m4.y, m4.z, m4.w};
      #pragma unroll
      for (int i = 0; i < 8; ++i)
        #pragma unroll
        for (int j = 0; j < 4; ++j)
          acc[i][j] += qv[i] * mv[j];
    }
  }

  // ---- phase B: intra-chunk causal attention over four 32-wide s-tiles ----
  const int sp = dvg * 2;   // this thread's score s-pair base
  for (int j = 0; j < 4; ++j) {
    __syncthreads();
    { // stage K-tile (transposed) + V-tile
      const int s = tid >> 3;
      const int d0 = (tid & 7) * 8;
      const size_t sg = (size_t)t0 + j * 32 + s;
      const float* krow =
          qk + ((((size_t)b * S_ + sg) * 2 + 1) * H_ + h) * D_ + d0;
      const float* vrow = v + (((size_t)b * S_ + sg) * H_ + h) * D_ + d0;
      float4 ka = *reinterpret_cast<const float4*>(krow);
      float4 kb = *reinterpret_cast<const float4*>(krow + 4);
      Kt[d0+0][s] = ka.x; Kt[d0+1][s] = ka.y; Kt[d0+2][s] = ka.z; Kt[d0+3][s] = ka.w;
      Kt[d0+4][s] = kb.x; Kt[d0+5][s] = kb.y; Kt[d0+6][s] = kb.z; Kt[d0+7][s] = kb.w;
      *reinterpret_cast<float4*>(&Vl[s][d0]) =
          *reinterpret_cast<const float4*>(vrow);
      *reinterpret_cast<float4*>(&Vl[s][d0 + 4]) =
          *reinterpret_cast<const float4*>(vrow + 4);
    }
    __syncthreads();
    const bool active = (j * 32 <= tb + 7);   // causal tile skip
    if (active) {
      float sc0[8] = {}, sc1[8] = {};
      #pragma unroll 4
      for (int d = 0; d < D_; ++d) {
        float4 qa = *reinterpret_cast<const float4*>(&Qt[d][tb]);
        float4 qb = *reinterpret_cast<const float4*>(&Qt[d][tb + 4]);
        float2 k2 = *reinterpret_cast<const float2*>(&Kt[d][sp]);
        float qv[8] = {qa.x, qa.y, qa.z, qa.w, qb.x, qb.y, qb.z, qb.w};
        #pragma unroll
        for (int i = 0; i < 8; ++i) {
          sc0[i] += qv[i] * k2.x;
          sc1[i] += qv[i] * k2.y;
        }
      }
      #pragma unroll
      for (int i = 0; i < 8; ++i) {
        int tl = tb + i;
        float2 w;
        w.x = (j * 32 + sp     <= tl) ? sc0[i] : 0.f;   // causal mask (incl diag)
        w.y = (j * 32 + sp + 1 <= tl) ? sc1[i] : 0.f;
        *reinterpret_cast<float2*>(&Sc[tl][sp]) = w;
      }
    }
    __syncthreads();
    if (active) {
      #pragma unroll 2
      for (int q4 = 0; q4 < 8; ++q4) {
        float4 v0 = *reinterpret_cast<const float4*>(&Vl[q4*4+0][dvg*4]);
        float4 v1 = *reinterpret_cast<const float4*>(&Vl[q4*4+1][dvg*4]);
        float4 v2 = *reinterpret_cast<const float4*>(&Vl[q4*4+2][dvg*4]);
        float4 v3 = *reinterpret_cast<const float4*>(&Vl[q4*4+3][dvg*4]);
        #pragma unroll
        for (int i = 0; i < 8; ++i) {
          float4 s4 = *reinterpret_cast<const float4*>(&Sc[tb + i][q4*4]);
          acc[i][0] += s4.x*v0.x + s4.y*v1.x + s4.z*v2.x + s4.w*v3.x;
          acc[i][1] += s4.x*v0.y + s4.y*v1.y + s4.z*v2.y + s4.w*v3.y;
          acc[i][2] += s4.x*v0.z + s4.y*v1.z + s4.z*v2.z + s4.w*v3.z;
          acc[i][3] += s4.x*v0.w + s4.y*v1.w + s4.z*v2.w + s4.w*v3.w;
        }
      }
    }
  }

  // ---- epilogue: scale by exp(-n) and store ----
  #pragma unroll
  for (int i = 0; i < 8; ++i) {
    const size_t t = (size_t)t0 + tb + i;
    float nv = nrm[((size_t)b * S_ + t) * H_ + h];
    float inv = expf(-nv);
    float4 o = make_float4(acc[i][0]*inv, acc[i][1]*inv,
                           acc[i][2]*inv, acc[i][3]*inv);
    *reinterpret_cast<float4*>(
        outp + (((size_t)b * S_ + t) * H_ + h) * D_ + dvg * 4) = o;
  }
}

extern "C" void kernel_launch(void* const* d_in, const int* in_sizes, int n_in,
                              void* d_out, int out_size, void* d_ws, size_t ws_size,
                              hipStream_t stream) {
  const float* qk  = (const float*)d_in[0];   // (B,S,2,H,D) f32
  const float* v   = (const float*)d_in[1];   // (B,S,H,D)   f32
  const float* nrm = (const float*)d_in[2];   // (B,S,H)     f32
  float* out = (float*)d_out;                 // (B,S,H,D)   f32
  float* kvbuf = (float*)d_ws;                // BH_*NC_*D*D floats = 16.8 MB

  kv_chunk_kernel<<<dim3(BH_ * NC_), dim3(256), 0, stream>>>(qk, v, kvbuf);
  prefix_kernel<<<dim3(BH_ * SPLIT_), dim3(256), 0, stream>>>(kvbuf);
  out_kernel<<<dim3(BH_ * NC_), dim3(256), 0, stream>>>(qk, v, nrm, kvbuf, out);
}